// Round 10
// baseline (115.521 us; speedup 1.0000x reference)
//
#include <hip/hip_runtime.h>
#include <hip/hip_bf16.h>

typedef _Float16 f16;
typedef f16 f16x8 __attribute__((ext_vector_type(8)));
typedef f16 f16x4 __attribute__((ext_vector_type(4)));
typedef float f32x4 __attribute__((ext_vector_type(4)));

#define IN_F 256
#define OUT_F 128
#define BM 64

// ---------------- fused prep: Wt transpose + segment bounds (no memset) ----------------
__global__ __launch_bounds__(256) void prep(const float* __restrict__ W,
                                            f16* __restrict__ Wt,
                                            const int* __restrict__ dst,
                                            int* __restrict__ rs,
                                            int* __restrict__ re,
                                            int E, int N) {
    int i = blockIdx.x * 256 + threadIdx.x;
    if (i < IN_F * OUT_F) {
        int k = i >> 7;          // row of W (0..255)
        int n = i & 127;         // col of W (0..127)
        Wt[n * IN_F + k] = (f16)W[i];
    }
    if (i < E) {
        int d = dst[i];
        if (i == 0) {
            rs[d] = 0;
            for (int v = 0; v < d; ++v) { rs[v] = 0; re[v] = 0; }
        } else {
            int a = dst[i - 1];
            if (a != d) {
                re[a] = i;
                rs[d] = i;
                for (int v = a + 1; v < d; ++v) { rs[v] = i; re[v] = i; }
            }
        }
        if (i == E - 1) {
            re[d] = E;
            for (int v = d + 1; v < N; ++v) { rs[v] = E; re[v] = E; }
        }
    }
}

// ---------------- GEMM: S = X @ W (fp16 MFMA), single-K-shot ----------------
// BM=64, BK=256 (full K). Whole 64x256 X tile staged in one burst (16 nt
// f32x4 loads/thread), f32->f16 cvt, XOR-swizzled LDS (32 KB), ONE barrier,
// 8 MFMA groups with B register double-buffer from L2-hot Wt.
// 5 blocks/CU co-resident (LDS-capped) smooth the HBM pipe + shrink tail.
// X loads and S stores nontemporal: X has zero reuse, S is re-read via L3.
__global__ __launch_bounds__(256, 5) void gemm_xw(const float* __restrict__ X,
                                                  const f16* __restrict__ Wt,
                                                  f16* __restrict__ S, int M) {
    __shared__ f16 sx[BM * IN_F] __attribute__((aligned(16)));   // 64x256 f16 = 32 KB

    const int w   = threadIdx.x >> 6;
    const int l   = threadIdx.x & 63;
    const int r   = l & 15;
    const int khi = l >> 4;
    const int wm = w >> 1, wn = w & 1;
    const int brow  = blockIdx.x * BM;
    const int mbase = wm * 32;
    const int nbase = wn * 64;

    f32x4 acc[2][4] = {};
    f16x8 bcur[4], bnxt[4];

    // B prefetch for MFMA group 0 (overlaps the X staging burst)
    #pragma unroll
    for (int n = 0; n < 4; ++n)
        bcur[n] = *(const f16x8*)(Wt + (size_t)(nbase + n * 16 + r) * IN_F + khi * 8);

    // ---- stage the whole 64x256 X tile as swizzled f16 ----
    #pragma unroll
    for (int jr = 0; jr < 4; ++jr) {
        const int rloc = w * 16 + jr * 4 + (l >> 4);
        int rg = brow + rloc; rg = rg < M ? rg : M - 1;
        const f32x4* xp = (const f32x4*)(X + (size_t)rg * IN_F + (l & 15) * 4);
        f32x4 xv[4];
        #pragma unroll
        for (int jc = 0; jc < 4; ++jc)
            xv[jc] = __builtin_nontemporal_load(xp + jc * 16);
        #pragma unroll
        for (int jc = 0; jc < 4; ++jc) {
            f16x4 hv = { (f16)xv[jc][0], (f16)xv[jc][1], (f16)xv[jc][2], (f16)xv[jc][3] };
            const int cf16 = (jc * 64 + (l & 15) * 4) ^ ((rloc & 15) << 3);
            *(f16x4*)&sx[rloc * IN_F + cf16] = hv;
        }
    }
    __syncthreads();

    // ---- 8 MFMA groups over K=256 ----
    #pragma unroll
    for (int kk = 0; kk < 8; ++kk) {
        if (kk < 7) {                      // prefetch next group's B fragments
            const int kg = (kk + 1) * 32 + khi * 8;
            #pragma unroll
            for (int n = 0; n < 4; ++n)
                bnxt[n] = *(const f16x8*)(Wt + (size_t)(nbase + n * 16 + r) * IN_F + kg);
        }
        f16x8 a[2];
        #pragma unroll
        for (int m = 0; m < 2; ++m) {
            const int arow = mbase + m * 16 + r;
            const int cf16 = (kk * 32 + khi * 8) ^ (r << 3);
            a[m] = *(const f16x8*)&sx[arow * IN_F + cf16];
        }
        #pragma unroll
        for (int m = 0; m < 2; ++m)
            #pragma unroll
            for (int n = 0; n < 4; ++n)
                acc[m][n] = __builtin_amdgcn_mfma_f32_16x16x32_f16(a[m], bcur[n], acc[m][n], 0, 0, 0);
        #pragma unroll
        for (int n = 0; n < 4; ++n) bcur[n] = bnxt[n];
    }

    // ---- epilogue: C/D layout D[(l>>4)*4 + i][l&15]; nontemporal stores ----
    #pragma unroll
    for (int m = 0; m < 2; ++m) {
        int row0 = brow + mbase + m * 16 + khi * 4;
        #pragma unroll
        for (int i = 0; i < 4; ++i) {
            int row = row0 + i;
            if (row < M) {
                #pragma unroll
                for (int n = 0; n < 4; ++n)
                    __builtin_nontemporal_store((f16)acc[m][n][i],
                        S + (size_t)row * OUT_F + nbase + n * 16 + r);
            }
        }
    }
}

// ---------------- aggregation: out[d] = tanh(bias + sum_e val[e]*S[src[e]]) ----------------
// (R4 version -- at the ~1 line/cy/XCD beyond-L2 fill wall: 186 MB / 73 us.)
__global__ __launch_bounds__(256) void aggregate(const f16* __restrict__ S,
                                                 const int* __restrict__ rs,
                                                 const int* __restrict__ re,
                                                 const int* __restrict__ esrc,
                                                 const float* __restrict__ eval,
                                                 const float* __restrict__ bias,
                                                 float* __restrict__ out, int N) {
    const int wave = threadIdx.x >> 6;
    const int lane = threadIdx.x & 63;
    const int node = blockIdx.x * 4 + wave;
    if (node >= N) return;

    const int g = lane >> 4;
    const int p = lane & 15;

    const int s = rs[node];
    const int e = re[node];

    float acc[8] = {};

    for (int base = s; base < e; base += 16) {
        int   se[4];
        float ve[4];
        #pragma unroll
        for (int j = 0; j < 4; ++j) {
            int ei  = base + j * 4 + g;
            int eic = min(ei, e - 1);
            se[j] = esrc[eic];
            ve[j] = eval[eic];
            if (ei >= e) ve[j] = 0.f;
        }
        f16x8 h[4];
        #pragma unroll
        for (int j = 0; j < 4; ++j)
            h[j] = *(const f16x8*)(S + (size_t)se[j] * OUT_F + p * 8);
        #pragma unroll
        for (int j = 0; j < 4; ++j)
            #pragma unroll
            for (int q = 0; q < 8; ++q)
                acc[q] += ve[j] * (float)h[j][q];
    }

    #pragma unroll
    for (int q = 0; q < 8; ++q) {
        acc[q] += __shfl_xor(acc[q], 16);
        acc[q] += __shfl_xor(acc[q], 32);
    }

    if (lane < 32) {
        const int half = lane >> 4;   // 0 or 1
        const int f0 = 8 * p + 4 * half;
        float4 bb = *(const float4*)(bias + f0);
        float4 o;
        o.x = tanhf(acc[4 * half + 0] + bb.x);
        o.y = tanhf(acc[4 * half + 1] + bb.y);
        o.z = tanhf(acc[4 * half + 2] + bb.z);
        o.w = tanhf(acc[4 * half + 3] + bb.w);
        *(float4*)(out + (size_t)node * OUT_F + f0) = o;
    }
}

extern "C" void kernel_launch(void* const* d_in, const int* in_sizes, int n_in,
                              void* d_out, int out_size, void* d_ws, size_t ws_size,
                              hipStream_t stream) {
    const float* X    = (const float*)d_in[0];
    const float* W    = (const float*)d_in[1];
    const float* bias = (const float*)d_in[2];
    const int*   esrc = (const int*)d_in[3];
    const int*   edst = (const int*)d_in[4];
    const float* eval = (const float*)d_in[5];
    float* out = (float*)d_out;

    const int N = in_sizes[0] / IN_F;      // 100000
    const int E = in_sizes[3];             // 1600000

    // workspace layout
    char* ws = (char*)d_ws;
    f16* Wt = (f16*)ws;                                   // 128*256*2 = 64 KB
    f16* S  = (f16*)(ws + 65536);                         // N*128*2 = 25.6 MB
    int* rs = (int*)(ws + 65536 + (size_t)N * OUT_F * 2); // N ints
    int* re = rs + N;

    prep<<<(E + 255) / 256, 256, 0, stream>>>(W, Wt, edst, rs, re, E, N);
    gemm_xw<<<(N + BM - 1) / BM, 256, 0, stream>>>(X, Wt, S, N);
    aggregate<<<(N + 3) / 4, 256, 0, stream>>>(S, rs, re, esrc, eval, bias, out, N);
}

// Round 11
// 108.867 us; speedup vs baseline: 1.0611x; 1.0611x over previous
//
#include <hip/hip_runtime.h>
#include <hip/hip_bf16.h>

typedef _Float16 f16;
typedef f16 f16x8 __attribute__((ext_vector_type(8)));
typedef f16 f16x4 __attribute__((ext_vector_type(4)));
typedef float f32x4 __attribute__((ext_vector_type(4)));

#define IN_F 256
#define OUT_F 128
#define BM 64

// ---------------- fused prep: Wt transpose + segment bounds (no memset) ----------------
__global__ __launch_bounds__(256) void prep(const float* __restrict__ W,
                                            f16* __restrict__ Wt,
                                            const int* __restrict__ dst,
                                            int* __restrict__ rs,
                                            int* __restrict__ re,
                                            int E, int N) {
    int i = blockIdx.x * 256 + threadIdx.x;
    if (i < IN_F * OUT_F) {
        int k = i >> 7;          // row of W (0..255)
        int n = i & 127;         // col of W (0..127)
        Wt[n * IN_F + k] = (f16)W[i];
    }
    if (i < E) {
        int d = dst[i];
        if (i == 0) {
            rs[d] = 0;
            for (int v = 0; v < d; ++v) { rs[v] = 0; re[v] = 0; }
        } else {
            int a = dst[i - 1];
            if (a != d) {
                re[a] = i;
                rs[d] = i;
                for (int v = a + 1; v < d; ++v) { rs[v] = i; re[v] = i; }
            }
        }
        if (i == E - 1) {
            re[d] = E;
            for (int v = d + 1; v < N; ++v) { rs[v] = E; re[v] = E; }
        }
    }
}

// ---------------- GEMM: S = X @ W (fp16 MFMA), single-K-shot ----------------
// BM=64, BK=256 (full K). Whole 64x256 X tile staged once: 16 float4 global
// loads per thread in flight (deep issue), f32->f16 cvt, XOR-swizzled f16 LDS
// tile (32 KB), ONE barrier, then 8 MFMA groups x 8 MFMA with B register
// double-buffer from L2-hot Wt. 4 blocks/CU co-resident smooth the HBM pipe.
// NOTE (R10): __launch_bounds__(256,5) regressed (VGPR cap ~102 -> spills);
// nontemporal X/S hints were neutral-to-negative. Keep (256,4), plain ops.
__global__ __launch_bounds__(256, 4) void gemm_xw(const float* __restrict__ X,
                                                  const f16* __restrict__ Wt,
                                                  f16* __restrict__ S, int M) {
    __shared__ f16 sx[BM * IN_F] __attribute__((aligned(16)));   // 64x256 f16 = 32 KB

    const int w   = threadIdx.x >> 6;
    const int l   = threadIdx.x & 63;
    const int r   = l & 15;
    const int khi = l >> 4;
    const int wm = w >> 1, wn = w & 1;
    const int brow  = blockIdx.x * BM;
    const int mbase = wm * 32;
    const int nbase = wn * 64;

    f32x4 acc[2][4] = {};
    f16x8 bcur[4], bnxt[4];

    // B prefetch for MFMA group 0 (overlaps the X staging burst)
    #pragma unroll
    for (int n = 0; n < 4; ++n)
        bcur[n] = *(const f16x8*)(Wt + (size_t)(nbase + n * 16 + r) * IN_F + khi * 8);

    // ---- stage the whole 64x256 X tile as swizzled f16 ----
    // instr (jr,jc): row = w*16 + jr*4 + (l>>4), colf32 = jc*64 + (l&15)*4
    #pragma unroll
    for (int jr = 0; jr < 4; ++jr) {
        const int rloc = w * 16 + jr * 4 + (l >> 4);
        int rg = brow + rloc; rg = rg < M ? rg : M - 1;
        const float* xp = X + (size_t)rg * IN_F + (l & 15) * 4;
        float4 xv[4];
        #pragma unroll
        for (int jc = 0; jc < 4; ++jc)
            xv[jc] = *(const float4*)(xp + jc * 64);
        #pragma unroll
        for (int jc = 0; jc < 4; ++jc) {
            f16x4 hv = { (f16)xv[jc].x, (f16)xv[jc].y, (f16)xv[jc].z, (f16)xv[jc].w };
            const int cf16 = (jc * 64 + (l & 15) * 4) ^ ((rloc & 15) << 3);
            *(f16x4*)&sx[rloc * IN_F + cf16] = hv;
        }
    }
    __syncthreads();

    // ---- 8 MFMA groups over K=256 ----
    #pragma unroll
    for (int kk = 0; kk < 8; ++kk) {
        if (kk < 7) {                      // prefetch next group's B fragments
            const int kg = (kk + 1) * 32 + khi * 8;
            #pragma unroll
            for (int n = 0; n < 4; ++n)
                bnxt[n] = *(const f16x8*)(Wt + (size_t)(nbase + n * 16 + r) * IN_F + kg);
        }
        f16x8 a[2];
        #pragma unroll
        for (int m = 0; m < 2; ++m) {
            const int arow = mbase + m * 16 + r;          // arow & 15 == r
            const int cf16 = (kk * 32 + khi * 8) ^ (r << 3);
            a[m] = *(const f16x8*)&sx[arow * IN_F + cf16];
        }
        #pragma unroll
        for (int m = 0; m < 2; ++m)
            #pragma unroll
            for (int n = 0; n < 4; ++n)
                acc[m][n] = __builtin_amdgcn_mfma_f32_16x16x32_f16(a[m], bcur[n], acc[m][n], 0, 0, 0);
        #pragma unroll
        for (int n = 0; n < 4; ++n) bcur[n] = bnxt[n];
    }

    // ---- epilogue: C/D layout D[(l>>4)*4 + i][l&15] ----
    #pragma unroll
    for (int m = 0; m < 2; ++m) {
        int row0 = brow + mbase + m * 16 + khi * 4;
        #pragma unroll
        for (int i = 0; i < 4; ++i) {
            int row = row0 + i;
            if (row < M) {
                #pragma unroll
                for (int n = 0; n < 4; ++n)
                    S[(size_t)row * OUT_F + nbase + n * 16 + r] = (f16)acc[m][n][i];
            }
        }
    }
}

// ---------------- aggregation: out[d] = tanh(bias + sum_e val[e]*S[src[e]]) ----------------
// (R4 version -- at the ~1 line/cy/XCD beyond-L2 fill wall: 186 MB / 73 us.)
// One wave per node. g = lane>>4: edge slot (4 in flight), p = lane&15: 16 B
// feature slice; 16 lanes x 16 B = one 256 B row per edge.
__global__ __launch_bounds__(256) void aggregate(const f16* __restrict__ S,
                                                 const int* __restrict__ rs,
                                                 const int* __restrict__ re,
                                                 const int* __restrict__ esrc,
                                                 const float* __restrict__ eval,
                                                 const float* __restrict__ bias,
                                                 float* __restrict__ out, int N) {
    const int wave = threadIdx.x >> 6;
    const int lane = threadIdx.x & 63;
    const int node = blockIdx.x * 4 + wave;
    if (node >= N) return;

    const int g = lane >> 4;
    const int p = lane & 15;

    const int s = rs[node];
    const int e = re[node];

    float acc[8] = {};

    for (int base = s; base < e; base += 16) {
        int   se[4];
        float ve[4];
        #pragma unroll
        for (int j = 0; j < 4; ++j) {
            int ei  = base + j * 4 + g;
            int eic = min(ei, e - 1);
            se[j] = esrc[eic];
            ve[j] = eval[eic];
            if (ei >= e) ve[j] = 0.f;
        }
        f16x8 h[4];
        #pragma unroll
        for (int j = 0; j < 4; ++j)
            h[j] = *(const f16x8*)(S + (size_t)se[j] * OUT_F + p * 8);
        #pragma unroll
        for (int j = 0; j < 4; ++j)
            #pragma unroll
            for (int q = 0; q < 8; ++q)
                acc[q] += ve[j] * (float)h[j][q];
    }

    #pragma unroll
    for (int q = 0; q < 8; ++q) {
        acc[q] += __shfl_xor(acc[q], 16);
        acc[q] += __shfl_xor(acc[q], 32);
    }

    if (lane < 32) {
        const int half = lane >> 4;   // 0 or 1
        const int f0 = 8 * p + 4 * half;
        float4 bb = *(const float4*)(bias + f0);
        float4 o;
        o.x = tanhf(acc[4 * half + 0] + bb.x);
        o.y = tanhf(acc[4 * half + 1] + bb.y);
        o.z = tanhf(acc[4 * half + 2] + bb.z);
        o.w = tanhf(acc[4 * half + 3] + bb.w);
        *(float4*)(out + (size_t)node * OUT_F + f0) = o;
    }
}

extern "C" void kernel_launch(void* const* d_in, const int* in_sizes, int n_in,
                              void* d_out, int out_size, void* d_ws, size_t ws_size,
                              hipStream_t stream) {
    const float* X    = (const float*)d_in[0];
    const float* W    = (const float*)d_in[1];
    const float* bias = (const float*)d_in[2];
    const int*   esrc = (const int*)d_in[3];
    const int*   edst = (const int*)d_in[4];
    const float* eval = (const float*)d_in[5];
    float* out = (float*)d_out;

    const int N = in_sizes[0] / IN_F;      // 100000
    const int E = in_sizes[3];             // 1600000

    // workspace layout
    char* ws = (char*)d_ws;
    f16* Wt = (f16*)ws;                                   // 128*256*2 = 64 KB
    f16* S  = (f16*)(ws + 65536);                         // N*128*2 = 25.6 MB
    int* rs = (int*)(ws + 65536 + (size_t)N * OUT_F * 2); // N ints
    int* re = rs + N;

    prep<<<(E + 255) / 256, 256, 0, stream>>>(W, Wt, edst, rs, re, E, N);
    gemm_xw<<<(N + BM - 1) / BM, 256, 0, stream>>>(X, Wt, S, N);
    aggregate<<<(N + 3) / 4, 256, 0, stream>>>(S, rs, re, esrc, eval, bias, out, N);
}